// Round 10
// baseline (158.447 us; speedup 1.0000x reference)
//
#include <hip/hip_runtime.h>
#include <hip/hip_bf16.h>

#if defined(__has_builtin)
#if __has_builtin(__builtin_amdgcn_exp2f)
#define EXP2F __builtin_amdgcn_exp2f
#endif
#if __has_builtin(__builtin_amdgcn_rcpf)
#define RCPF __builtin_amdgcn_rcpf
#endif
#endif
#ifndef EXP2F
#define EXP2F exp2f
#endif
#ifndef RCPF
#define RCPF(x) (1.0f / (x))
#endif

// Sizes (fixed by the problem)
#define B_  8
#define Q_  256
#define K_  1024
#define D_  256
#define H_  128
#define DV_ 128

#define CSL 2.8853900817779268f   // 2*log2(e)
#define L2E 1.4426950408889634f   // log2(e)

// Workspace layout (floats). ~13.7 MB used.
#define QE_OFF   0                // qE   [B*Q][H]              = 262144
#define KE_OFF   262144           // kET2 [B][64 p][K] float2   = 1048576
#define WPK_OFF  1310720          // wpk  [64] float4           = 256
#define AVP_OFF  1310976          // avpart [8 kc][2048][128]   = 2097152
#define SP_OFF   3408128          // spart  [8 kc][2048]        = 16384

// ---------------------------------------------------------------------------
// proj_kernel: unchanged (stable, never in top-5).
// ---------------------------------------------------------------------------
__global__ __launch_bounds__(256) void proj_kernel(
    const float* __restrict__ queries, const float* __restrict__ keys,
    const float* __restrict__ Wq, const float* __restrict__ Wk,
    const float* __restrict__ w_v,
    float* __restrict__ qE, float2* __restrict__ kET2, float* __restrict__ wpk)
{
    __shared__ __align__(16) float As[64][68];   // [d][row], pad 68
    __shared__ __align__(16) float Ws[64][64];   // [d][col]

    const int tid = threadIdx.x;
    const int blk = blockIdx.x;
    const bool isQ = blk < 64;
    const int t = isQ ? blk : (blk - 64);
    const int rowtile = t >> 1;
    const int cbase = (t & 1) * 64;
    const int row0 = rowtile * 64;
    const float* A = isQ ? (queries + row0 * D_) : (keys + row0 * D_);
    const float* W = isQ ? Wq : Wk;

    float acc[4][4];
#pragma unroll
    for (int i = 0; i < 4; i++)
#pragma unroll
        for (int j = 0; j < 4; j++) acc[i][j] = 0.f;

    const int lr  = tid & 63;
    const int ldb = (tid >> 6) * 16;
    const int r4  = (tid >> 4) * 4;
    const int c4  = (tid & 15) * 4;

    for (int d0 = 0; d0 < D_; d0 += 64) {
#pragma unroll
        for (int j = 0; j < 4; j++) {
            const float4 a = *(const float4*)&A[lr * D_ + d0 + ldb + j * 4];
            As[ldb + j * 4 + 0][lr] = a.x;
            As[ldb + j * 4 + 1][lr] = a.y;
            As[ldb + j * 4 + 2][lr] = a.z;
            As[ldb + j * 4 + 3][lr] = a.w;
        }
#pragma unroll
        for (int l = 0; l < 4; l++) {
            const int idx = tid + l * 256;
            const int rr = idx >> 4, cc = (idx & 15) * 4;
            *(float4*)&Ws[rr][cc] = *(const float4*)&W[(d0 + rr) * H_ + cbase + cc];
        }
        __syncthreads();
#pragma unroll 4
        for (int d = 0; d < 64; d++) {
            const float4 a4 = *(const float4*)&As[d][r4];
            const float4 w4 = *(const float4*)&Ws[d][c4];
            const float ar[4] = {a4.x, a4.y, a4.z, a4.w};
#pragma unroll
            for (int i = 0; i < 4; i++) {
                acc[i][0] = fmaf(ar[i], w4.x, acc[i][0]);
                acc[i][1] = fmaf(ar[i], w4.y, acc[i][1]);
                acc[i][2] = fmaf(ar[i], w4.z, acc[i][2]);
                acc[i][3] = fmaf(ar[i], w4.w, acc[i][3]);
            }
        }
        __syncthreads();
    }

#pragma unroll
    for (int i = 0; i < 4; i++) {
        float e[4];
#pragma unroll
        for (int j = 0; j < 4; j++) e[j] = EXP2F(CSL * acc[i][j]);
        const int row = row0 + r4 + i;
        if (isQ) {
            *(float4*)&qE[row * H_ + cbase + c4] = make_float4(e[0], e[1], e[2], e[3]);
        } else {
            const int b = row >> 10, k = row & 1023;
            const int p0 = (cbase + c4) >> 1;
            kET2[(size_t)(b * 64 + p0) * K_ + k]     = make_float2(e[0], e[1]);
            kET2[(size_t)(b * 64 + p0 + 1) * K_ + k] = make_float2(e[2], e[3]);
        }
    }

    if (blk == 0 && tid < 64) {
        const float w1 = -2.0f * L2E * w_v[2 * tid];
        const float w2 = -2.0f * L2E * w_v[2 * tid + 1];
        *(float4*)&wpk[tid * 4] = make_float4(w1, w2, w1 + w2, 0.f);
    }
}

// ---------------------------------------------------------------------------
// attn_kernel: 2048 blocks x 512 threads, UNIFORM work items.
// Item = (b, qt: 8 q-rows, kc: 128-k chunk), enumerated only over ACTIVE
// chunks (kc < ceil(vl_b/128)) via uniform prefix decode from valid_lens.
// Blocks with idx >= T exit (all at the tail of dispatch order; survivors
// stripe ~evenly across CUs and all cost the same -> makespan ~ mean).
// Thread = (kl = tid&127, rep = tid>>7): rep splits the 64 h-pairs into 4
// ranges (log-domain scores are additive); EVERY thread handles all 8 q-rows
// so q/wpk operands stay block-uniform -> scalar s_load (R4's 62%-VALU
// pattern). Each ek pair loaded once per block: ~64 KB/item L2 traffic.
// h-pairing: w1/(1+x1)+w2/(1+x2) = [(w1+w2)+w1*x2+w2*x1]/[(1+x1)(1+x2)].
// ---------------------------------------------------------------------------
__global__ __launch_bounds__(512, 8) void attn_kernel(
    const float* __restrict__ qE,       // [B*Q][H] = e^{2q}
    const float2* __restrict__ kET2,    // [B][64][K] h-pairs of e^{2k}
    const float* __restrict__ values,   // [B][K][DV]
    const int*   __restrict__ valid_lens,
    const float* __restrict__ wpk,      // [64] float4 (w1,w2,w1+w2,0)
    float* __restrict__ avpart,         // [8][2048][128]
    float* __restrict__ spart)          // [8][2048]
{
    __shared__ __align__(16) float scP[4][128][8];  // 16 KB  rep-partial scores
    __shared__ __align__(16) float sc[128][8];      // 4 KB   final p-values
    __shared__ __align__(16) float psum[2][8];

    const int tid = threadIdx.x;
    const int idx = blockIdx.x;

    // ---- uniform item decode from valid_lens ----
    int cum = 0, fb = 0, flocal = 0;
#pragma unroll
    for (int bb = 0; bb < 8; bb++) {
        const int v = valid_lens[bb];
        const int n = ((v + 127) >> 7) * 32;     // active chunks * 32 q-tiles
        if (idx >= cum && idx < cum + n) { fb = bb; flocal = idx - cum; }
        cum += n;
    }
    if (idx >= cum) return;                      // uniform: whole block exits
    const int b  = fb;
    const int kc = flocal >> 5;                  // 0..ceil(vl/128)-1
    const int qt = flocal & 31;
    const int q0 = qt * 8;
    const int vl = valid_lens[b];

    const int kl  = tid & 127;
    const int rep = tid >> 7;                    // 0..3 -> p in [16rep,16rep+16)
    const int k   = kc * 128 + kl;
    const float* qp = qE + (b * Q_ + q0) * H_;   // block-uniform -> s_load

    float acc[8];
#pragma unroll
    for (int q = 0; q < 8; q++) acc[q] = 0.f;

    if (k < vl) {
        const float2* kb = kET2 + (size_t)(b * 64) * K_ + k;
#pragma unroll 4
        for (int pp = 0; pp < 16; pp++) {
            const int p = rep * 16 + pp;
            const float2 ek = kb[(size_t)p * K_];
            const float4 wp = *(const float4*)&wpk[p * 4];
#pragma unroll
            for (int q = 0; q < 8; q++) {
                const float2 qq = *(const float2*)&qp[q * H_ + 2 * p];
                const float x1 = qq.x * ek.x, x2 = qq.y * ek.y;
                const float e1 = x1 + 1.f;
                const float d  = fmaf(e1, x2, e1);
                float n = fmaf(wp.y, x1, wp.z);
                n = fmaf(wp.x, x2, n);
                acc[q] = fmaf(n, RCPF(d), acc[q]);
            }
        }
    }
    *(float4*)&scP[rep][kl][0] = make_float4(acc[0], acc[1], acc[2], acc[3]);
    *(float4*)&scP[rep][kl][4] = make_float4(acc[4], acc[5], acc[6], acc[7]);
    __syncthreads();

    // ---- combine reps + exp + mask + row sums (threads 0..127) ----
    if (tid < 128) {
        const bool valid = (kc * 128 + tid) < vl;
        float pv[8];
#pragma unroll
        for (int h = 0; h < 2; h++) {
            float4 s = *(const float4*)&scP[0][tid][h * 4];
            const float4 s1 = *(const float4*)&scP[1][tid][h * 4];
            const float4 s2 = *(const float4*)&scP[2][tid][h * 4];
            const float4 s3 = *(const float4*)&scP[3][tid][h * 4];
            s.x += s1.x + s2.x + s3.x;  s.y += s1.y + s2.y + s3.y;
            s.z += s1.z + s2.z + s3.z;  s.w += s1.w + s2.w + s3.w;
            pv[h * 4 + 0] = valid ? EXP2F(s.x) : 0.f;
            pv[h * 4 + 1] = valid ? EXP2F(s.y) : 0.f;
            pv[h * 4 + 2] = valid ? EXP2F(s.z) : 0.f;
            pv[h * 4 + 3] = valid ? EXP2F(s.w) : 0.f;
        }
        *(float4*)&sc[tid][0] = make_float4(pv[0], pv[1], pv[2], pv[3]);
        *(float4*)&sc[tid][4] = make_float4(pv[4], pv[5], pv[6], pv[7]);
#pragma unroll
        for (int sh = 32; sh > 0; sh >>= 1) {
#pragma unroll
            for (int q = 0; q < 8; q++) pv[q] += __shfl_xor(pv[q], sh);
        }
        if ((tid & 63) == 0) {
            const int w = tid >> 6;
            *(float4*)&psum[w][0] = make_float4(pv[0], pv[1], pv[2], pv[3]);
            *(float4*)&psum[w][4] = make_float4(pv[4], pv[5], pv[6], pv[7]);
        }
    }
    __syncthreads();
    if (tid < 8)
        spart[kc * 2048 + b * Q_ + q0 + tid] = psum[0][tid] + psum[1][tid];

    // ---- partial AV: thread = (q = tid>>6, khalf = (tid>>5)&1, v4) ----
    const int q     = tid >> 6;          // 0..7
    const int lane  = tid & 63;
    const int khalf = lane >> 5;         // 0/1 -> 64-k halves
    const int v4    = (lane & 31) * 4;
    const int kb0   = kc * 128 + khalf * 64;
    const float* vb = values + (size_t)b * (K_ * DV_) + (size_t)kb0 * DV_ + v4;
    float a0 = 0.f, a1 = 0.f, a2 = 0.f, a3 = 0.f;
    const int rem = vl - kb0;
    const int imax = rem <= 0 ? 0 : (rem > 64 ? 64 : rem);
#pragma unroll 2
    for (int i = 0; i < imax; i++) {
        const float4 vv = *(const float4*)&vb[i * DV_];
        const float pp = sc[khalf * 64 + i][q];   // broadcast across 32 lanes
        a0 = fmaf(pp, vv.x, a0);
        a1 = fmaf(pp, vv.y, a1);
        a2 = fmaf(pp, vv.z, a2);
        a3 = fmaf(pp, vv.w, a3);
    }
    a0 += __shfl_xor(a0, 32);
    a1 += __shfl_xor(a1, 32);
    a2 += __shfl_xor(a2, 32);
    a3 += __shfl_xor(a3, 32);
    if (khalf == 0)
        *(float4*)&avpart[(size_t)(kc * 2048 + b * Q_ + q0 + q) * DV_ + v4] =
            make_float4(a0, a1, a2, a3);
}

// ---------------------------------------------------------------------------
// combine_kernel: out[row][v] = sum_{g<ceil(vl/128)} avpart[g][row][v]
//                               * rcp(sum_g spart[g][row]).
// ---------------------------------------------------------------------------
__global__ __launch_bounds__(256) void combine_kernel(
    const float* __restrict__ avpart, const float* __restrict__ spart,
    const int* __restrict__ valid_lens, float* __restrict__ out)
{
    const int t = blockIdx.x * 256 + threadIdx.x;   // 0..65535
    const int idx = t * 4;
    const int row = idx >> 7;                       // 0..2047
    const int b = row >> 8;
    const int vl = valid_lens[b];
    const int np = (vl + 127) >> 7;                 // 1..8 active parts

    float ax = 0.f, ay = 0.f, az = 0.f, aw = 0.f, s = 0.f;
    for (int g = 0; g < np; g++) {
        const float4 r = *(const float4*)&avpart[(size_t)g * 2048 * DV_ + idx];
        ax += r.x; ay += r.y; az += r.z; aw += r.w;
        s += spart[g * 2048 + row];
    }
    const float rr = RCPF(s);
    *(float4*)&out[idx] = make_float4(ax * rr, ay * rr, az * rr, aw * rr);
}

extern "C" void kernel_launch(void* const* d_in, const int* in_sizes, int n_in,
                              void* d_out, int out_size, void* d_ws, size_t ws_size,
                              hipStream_t stream) {
    const float* queries    = (const float*)d_in[0];  // [8,256,256]
    const float* keys       = (const float*)d_in[1];  // [8,1024,256]
    const float* values     = (const float*)d_in[2];  // [8,1024,128]
    const int*   valid_lens = (const int*)d_in[3];    // [8]
    const float* W_q        = (const float*)d_in[4];  // [256,128]
    const float* W_k        = (const float*)d_in[5];  // [256,128]
    const float* w_v        = (const float*)d_in[6];  // [128]
    float* out = (float*)d_out;

    float*  ws     = (float*)d_ws;
    float*  qE     = ws + QE_OFF;
    float2* kET2   = (float2*)(ws + KE_OFF);
    float*  wpk    = ws + WPK_OFF;
    float*  avpart = ws + AVP_OFF;
    float*  spart  = ws + SP_OFF;

    proj_kernel<<<320, 256, 0, stream>>>(queries, keys, W_q, W_k, w_v, qE, kET2, wpk);
    attn_kernel<<<2048, 512, 0, stream>>>(qE, kET2, values, valid_lens, wpk, avpart, spart);
    combine_kernel<<<256, 256, 0, stream>>>(avpart, spart, valid_lens, out);
}